// Round 1
// baseline (373.335 us; speedup 1.0000x reference)
//
#include <hip/hip_runtime.h>
#include <math.h>

namespace {

constexpr int kB = 512, kI = 1152, kD = 8, kJ = 10, kC = 16;
constexpr int TB = 2;        // batches per block
constexpr int THREADS = 512; // 8 waves
constexpr int CHUNK = 512;   // i-rows per LDS transpose chunk
constexpr int PAD = 17;      // LDS row stride in floats (odd -> <=2-way bank conflict)
constexpr float EPS = 1e-7f;

__launch_bounds__(THREADS, 2)
__global__ void digitcaps_fused(const float* __restrict__ x,
                                const float* __restrict__ W,
                                float* __restrict__ out) {
  __shared__ float lds[TB][CHUNK * PAD];   // 69,632 B transpose buffer
  __shared__ float sredS[8][kC];           // per-wave partial s vectors
  __shared__ float sredM[8];               // per-wave max
  __shared__ float sredZ[8];               // per-wave exp-sum

  const int t    = threadIdx.x;
  const int lane = t & 63;
  const int wid  = t >> 6;
  const int c4   = t & 3;   // which group of 4 output channels (phase 1)
  const int g    = t >> 2;  // which i within a 128-row stripe (phase 1)

  const int bid = blockIdx.x;
  const int j   = bid >> 8;            // 256 blocks per j (j-major -> W[j] stays hot in each XCD L2)
  const int b0  = (bid & 255) * TB;

  // Register-resident x_hat rows: thread t owns i = t, t+512, (t+1024 if t<128)
  float xh[TB][3][kC];
  #pragma unroll
  for (int tb = 0; tb < TB; ++tb)
    #pragma unroll
    for (int cc = 0; cc < kC; ++cc) xh[tb][2][cc] = 0.f;

  // ---------------- Phase 1: x_hat[b,j,i,c] = sum_d x[b,i,d] * W[j,i,d,c] ----
  #pragma unroll
  for (int ch = 0; ch < 3; ++ch) {
    const int iters = (ch < 2) ? (CHUNK / 128) : 1;  // chunk 2 has 128 rows
    #pragma unroll
    for (int it = 0; it < iters; ++it) {
      const int il = g + (it << 7);          // 0..511 (or 0..127)
      const int i  = ch * CHUNK + il;
      const float* Wp = W + (size_t)(j * kI + i) * (kD * kC) + (c4 << 2);
      const float4* xp0 = reinterpret_cast<const float4*>(x + (size_t)((b0 + 0) * kI + i) * kD);
      const float4* xp1 = reinterpret_cast<const float4*>(x + (size_t)((b0 + 1) * kI + i) * kD);
      float xr0[8], xr1[8];
      {
        float4 v0 = xp0[0], v1 = xp0[1];
        xr0[0]=v0.x; xr0[1]=v0.y; xr0[2]=v0.z; xr0[3]=v0.w;
        xr0[4]=v1.x; xr0[5]=v1.y; xr0[6]=v1.z; xr0[7]=v1.w;
        v0 = xp1[0]; v1 = xp1[1];
        xr1[0]=v0.x; xr1[1]=v0.y; xr1[2]=v0.z; xr1[3]=v0.w;
        xr1[4]=v1.x; xr1[5]=v1.y; xr1[6]=v1.z; xr1[7]=v1.w;
      }
      float a0[4] = {0.f,0.f,0.f,0.f}, a1[4] = {0.f,0.f,0.f,0.f};
      #pragma unroll
      for (int d = 0; d < 8; ++d) {
        const float4 w = *reinterpret_cast<const float4*>(Wp + d * kC);
        a0[0] += xr0[d] * w.x; a0[1] += xr0[d] * w.y;
        a0[2] += xr0[d] * w.z; a0[3] += xr0[d] * w.w;
        a1[0] += xr1[d] * w.x; a1[1] += xr1[d] * w.y;
        a1[2] += xr1[d] * w.z; a1[3] += xr1[d] * w.w;
      }
      const int base = il * PAD + (c4 << 2);
      #pragma unroll
      for (int cc = 0; cc < 4; ++cc) {
        lds[0][base + cc] = a0[cc];
        lds[1][base + cc] = a1[cc];
      }
    }
    __syncthreads();
    if (ch < 2 || t < 128) {
      #pragma unroll
      for (int cc = 0; cc < kC; ++cc) {
        xh[0][ch][cc] = lds[0][t * PAD + cc];
        xh[1][ch][cc] = lds[1][t * PAD + cc];
      }
    }
    __syncthreads();
  }

  // ---------------- Phase 2: 3 routing iterations, all on-chip --------------
  const bool v3 = (t < 128);  // third owned i-row valid?
  #pragma unroll
  for (int tb = 0; tb < TB; ++tb) {
    float bl0 = 0.f, bl1 = 0.f, bl2 = 0.f;  // routing logits for owned rows
    #pragma unroll
    for (int itr = 0; itr < 3; ++itr) {
      // --- softmax max over i (block reduction) ---
      float mloc = fmaxf(bl0, bl1);
      if (v3) mloc = fmaxf(mloc, bl2);
      #pragma unroll
      for (int off = 1; off < 64; off <<= 1)
        mloc = fmaxf(mloc, __shfl_xor(mloc, off, 64));
      if (lane == 0) sredM[wid] = mloc;
      __syncthreads();
      float m = sredM[0];
      #pragma unroll
      for (int w = 1; w < 8; ++w) m = fmaxf(m, sredM[w]);

      // --- e_i, partial Z and partial s[c] ---
      const float e0 = expf(bl0 - m);
      const float e1 = expf(bl1 - m);
      const float e2 = v3 ? expf(bl2 - m) : 0.f;
      float zs = e0 + e1 + e2;
      float ps[kC];
      #pragma unroll
      for (int cc = 0; cc < kC; ++cc)
        ps[cc] = e0 * xh[tb][0][cc] + e1 * xh[tb][1][cc] + e2 * xh[tb][2][cc];
      #pragma unroll
      for (int off = 1; off < 64; off <<= 1) {
        zs += __shfl_xor(zs, off, 64);
        #pragma unroll
        for (int cc = 0; cc < kC; ++cc) ps[cc] += __shfl_xor(ps[cc], off, 64);
      }
      if (lane == 0) {
        sredZ[wid] = zs;
        #pragma unroll
        for (int cc = 0; cc < kC; ++cc) sredS[wid][cc] = ps[cc];
      }
      __syncthreads();

      // --- combine wave partials (uniform across threads) ---
      float Z = 0.f;
      #pragma unroll
      for (int w = 0; w < 8; ++w) Z += sredZ[w];
      const float invZ = 1.f / Z;
      float s[kC];
      float ssq = 0.f;
      #pragma unroll
      for (int cc = 0; cc < kC; ++cc) {
        float acc = 0.f;
        #pragma unroll
        for (int w = 0; w < 8; ++w) acc += sredS[w][cc];
        s[cc] = acc * invZ;
        ssq += s[cc] * s[cc];
      }
      const float norm = sqrtf(ssq);
      const float fac = ssq / ((1.f + ssq) * (norm + EPS));

      if (itr < 2) {
        // --- agreement update: b_i += dot(v, x_hat[i,:]) ---
        float d0 = 0.f, d1 = 0.f, d2 = 0.f;
        #pragma unroll
        for (int cc = 0; cc < kC; ++cc) {
          const float vc = fac * s[cc];
          d0 += vc * xh[tb][0][cc];
          d1 += vc * xh[tb][1][cc];
          d2 += vc * xh[tb][2][cc];
        }
        bl0 += d0; bl1 += d1; if (v3) bl2 += d2;
      } else {
        // --- final v write: thread t<16 writes channel t ---
        if (t < kC) {
          float acc = 0.f;
          #pragma unroll
          for (int w = 0; w < 8; ++w) acc += sredS[w][t];
          out[((size_t)(b0 + tb) * kJ + j) * kC + t] = fac * (acc * invZ);
        }
      }
      // no extra barrier needed: sredM reads complete before barrier-2 of this
      // iteration; sredZ/sredS reads complete before barrier-1 of the next.
    }
  }
}

}  // namespace

extern "C" void kernel_launch(void* const* d_in, const int* in_sizes, int n_in,
                              void* d_out, int out_size, void* d_ws, size_t ws_size,
                              hipStream_t stream) {
  (void)in_sizes; (void)n_in; (void)d_ws; (void)ws_size; (void)out_size;
  const float* x = reinterpret_cast<const float*>(d_in[0]);
  const float* W = reinterpret_cast<const float*>(d_in[1]);
  float* out = reinterpret_cast<float*>(d_out);
  const int grid = (kB / TB) * kJ;  // 2560 blocks, j-major
  digitcaps_fused<<<grid, THREADS, 0, stream>>>(x, W, out);
}